// Round 10
// baseline (805.577 us; speedup 1.0000x reference)
//
#include <hip/hip_runtime.h>

#define PI2F 6.283185307179586476f

// ---------------------------------------------------------------------------
// 16-point DFT, natural order in/out, fully unrolled (two radix-4 layers).
// ---------------------------------------------------------------------------
__device__ __forceinline__ void dft16(float* xr, float* xi)
{
    const float W16R[16] = {1.f, 1.f, 1.f, 1.f,
                            1.f, 0.92387953251f, 0.70710678119f, 0.38268343236f,
                            1.f, 0.70710678119f, 0.f, -0.70710678119f,
                            1.f, 0.38268343236f, -0.70710678119f, -0.92387953251f};
    const float W16I[16] = {0.f, 0.f, 0.f, 0.f,
                            0.f, -0.38268343236f, -0.70710678119f, -0.92387953251f,
                            0.f, -0.70710678119f, -1.f, -0.70710678119f,
                            0.f, -0.92387953251f, -0.70710678119f, 0.38268343236f};

    float br[16], bi[16];
#pragma unroll
    for (int jl = 0; jl < 4; ++jl) {
        float a0r = xr[jl],      a0i = xi[jl];
        float a1r = xr[jl + 4],  a1i = xi[jl + 4];
        float a2r = xr[jl + 8],  a2i = xi[jl + 8];
        float a3r = xr[jl + 12], a3i = xi[jl + 12];
        float s02r = a0r + a2r, s02i = a0i + a2i;
        float d02r = a0r - a2r, d02i = a0i - a2i;
        float s13r = a1r + a3r, s13i = a1i + a3i;
        float d13r = a1r - a3r, d13i = a1i - a3i;
        br[jl + 0]  = s02r + s13r;  bi[jl + 0]  = s02i + s13i;
        br[jl + 4]  = d02r + d13i;  bi[jl + 4]  = d02i - d13r;
        br[jl + 8]  = s02r - s13r;  bi[jl + 8]  = s02i - s13i;
        br[jl + 12] = d02r - d13i;  bi[jl + 12] = d02i + d13r;
    }
#pragma unroll
    for (int pos = 0; pos < 16; ++pos) {
        float wr = W16R[pos], wi = W16I[pos];
        float tr = br[pos] * wr - bi[pos] * wi;
        bi[pos]  = br[pos] * wi + bi[pos] * wr;
        br[pos]  = tr;
    }
#pragma unroll
    for (int rl = 0; rl < 4; ++rl) {
        float a0r = br[4 * rl + 0], a0i = bi[4 * rl + 0];
        float a1r = br[4 * rl + 1], a1i = bi[4 * rl + 1];
        float a2r = br[4 * rl + 2], a2i = bi[4 * rl + 2];
        float a3r = br[4 * rl + 3], a3i = bi[4 * rl + 3];
        float s02r = a0r + a2r, s02i = a0i + a2i;
        float d02r = a0r - a2r, d02i = a0i - a2i;
        float s13r = a1r + a3r, s13i = a1i + a3i;
        float d13r = a1r - a3r, d13i = a1i - a3i;
        xr[rl + 0]  = s02r + s13r;  xi[rl + 0]  = s02i + s13i;
        xr[rl + 4]  = d02r + d13i;  xi[rl + 4]  = d02i - d13r;
        xr[rl + 8]  = s02r - s13r;  xi[rl + 8]  = s02i - s13i;
        xr[rl + 12] = d02r - d13i;  xi[rl + 12] = d02i + d13r;
    }
}

// ---------------------------------------------------------------------------
// Pass 1 (s = 1): radix-256 Stockham with LDS-staged contiguous stores (r8).
// ---------------------------------------------------------------------------
__global__ __launch_bounds__(256) void fft256_first(const float2* __restrict__ xc,
                                                    float2* __restrict__ yc,
                                                    int Nq,         // M/256
                                                    float m_inv,    // 1/M
                                                    float m16_inv)  // 16/M
{
    __shared__ __align__(16) float lds[16 * 260 + 4];

    const int tid = threadIdx.x;
    const int f   = tid & 15;
    const int k   = tid >> 4;
    const int t   = blockIdx.x * 16 + f;

    float ar[16], ai[16];
#pragma unroll
    for (int j2 = 0; j2 < 16; ++j2) {
        float2 v = xc[t + (k + 16 * j2) * Nq];
        ar[j2] = v.x;
        ai[j2] = v.y;
    }

    dft16(ar, ai);

    {
        const float mf = (float)(k * Nq + t);
        float ang = -PI2F * (mf * m_inv);
        float w1i, w1r;
        __sincosf(ang, &w1i, &w1r);
        float cw = w1r, sw = w1i;
#pragma unroll
        for (int r1 = 1; r1 < 16; ++r1) {
            float tr = ar[r1] * cw - ai[r1] * sw;
            ai[r1]   = ar[r1] * sw + ai[r1] * cw;
            ar[r1]   = tr;
            float ncw = cw * w1r - sw * w1i;
            sw = cw * w1i + sw * w1r;
            cw = ncw;
        }
    }

    const int wbase = f * 260 + k * 16;
    const int rbase = f * 260 + k;

    float er[16], ei[16];

#pragma unroll
    for (int v = 0; v < 4; ++v)
        *(float4*)&lds[wbase + 4 * v] =
            make_float4(ar[4 * v], ar[4 * v + 1], ar[4 * v + 2], ar[4 * v + 3]);
    __syncthreads();
#pragma unroll
    for (int jj = 0; jj < 16; ++jj)
        er[jj] = lds[rbase + jj * 16];
    __syncthreads();

#pragma unroll
    for (int v = 0; v < 4; ++v)
        *(float4*)&lds[wbase + 4 * v] =
            make_float4(ai[4 * v], ai[4 * v + 1], ai[4 * v + 2], ai[4 * v + 3]);
    __syncthreads();
#pragma unroll
    for (int jj = 0; jj < 16; ++jj)
        ei[jj] = lds[rbase + jj * 16];

    dft16(er, ei);

    {
        float ang2 = -PI2F * ((float)t * m16_inv);
        float u1i, u1r;
        __sincosf(ang2, &u1i, &u1r);
        float cw = u1r, sw = u1i;
#pragma unroll
        for (int r2 = 1; r2 < 16; ++r2) {
            float tr = er[r2] * cw - ei[r2] * sw;
            ei[r2]   = er[r2] * sw + ei[r2] * cw;
            er[r2]   = tr;
            float ncw = cw * u1r - sw * u1i;
            sw = cw * u1i + sw * u1r;
            cw = ncw;
        }
    }

    float2* img = (float2*)lds;
    __syncthreads();
#pragma unroll
    for (int b = 0; b < 2; ++b) {
        if ((f >> 3) == b) {
            const int fr = f & 7;
#pragma unroll
            for (int r2 = 0; r2 < 16; ++r2)
                img[fr * 258 + k + 16 * r2] = make_float2(er[r2], ei[r2]);
        }
        __syncthreads();
        const int base = (blockIdx.x * 16 + 8 * b) * 256;
#pragma unroll
        for (int i = 0; i < 8; ++i)
            yc[base + i * 256 + tid] = img[i * 258 + tid];
        if (b == 0) __syncthreads();
    }
}

// ---------------------------------------------------------------------------
// Middle pass (s = 256): radix-256 Stockham, 512 threads = 32 f x 16 k (r9).
// ---------------------------------------------------------------------------
__global__ __launch_bounds__(512) void fft256_mid(const float2* __restrict__ xc,
                                                  float2* __restrict__ yc,
                                                  int Nq,        // M/256
                                                  int sl,        // log2(s)
                                                  float n_inv,   // 1/n
                                                  float n16_inv) // 16/n
{
    __shared__ float lds[32 * 257 + 4];

    const int tid = threadIdx.x;
    const int f   = tid & 31;
    const int k   = tid >> 5;
    const int t   = blockIdx.x * 32 + f;
    const int s   = 1 << sl;
    const int q   = t & (s - 1);
    const int p   = t >> sl;

    float ar[16], ai[16];
#pragma unroll
    for (int j2 = 0; j2 < 16; ++j2) {
        float2 v = xc[t + (k + 16 * j2) * Nq];
        ar[j2] = v.x;
        ai[j2] = v.y;
    }

    dft16(ar, ai);

    {
        const int   m  = k * (Nq >> sl) + p;
        float ang = -PI2F * ((float)m * n_inv);
        float w1i, w1r;
        __sincosf(ang, &w1i, &w1r);
        float cw = w1r, sw = w1i;
#pragma unroll
        for (int r1 = 1; r1 < 16; ++r1) {
            float tr = ar[r1] * cw - ai[r1] * sw;
            ai[r1]   = ar[r1] * sw + ai[r1] * cw;
            ar[r1]   = tr;
            float ncw = cw * w1r - sw * w1i;
            sw = cw * w1i + sw * w1r;
            cw = ncw;
        }
    }

    const int wbase = f * 257 + k * 16;
    const int rbase = f * 257 + k;

    float er[16], ei[16];

#pragma unroll
    for (int r1 = 0; r1 < 16; ++r1)
        lds[wbase + r1] = ar[r1];
    __syncthreads();
#pragma unroll
    for (int jj = 0; jj < 16; ++jj)
        er[jj] = lds[rbase + jj * 16];
    __syncthreads();

#pragma unroll
    for (int r1 = 0; r1 < 16; ++r1)
        lds[wbase + r1] = ai[r1];
    __syncthreads();
#pragma unroll
    for (int jj = 0; jj < 16; ++jj)
        ei[jj] = lds[rbase + jj * 16];

    dft16(er, ei);

    const int dstbase = q + ((256 * p + k) << sl);
    float ang2 = -PI2F * ((float)p * n16_inv);
    float u1i, u1r;
    __sincosf(ang2, &u1i, &u1r);

    yc[dstbase] = make_float2(er[0], ei[0]);
    float cw = u1r, sw = u1i;
#pragma unroll
    for (int r2 = 1; r2 < 16; ++r2) {
        int dst = dstbase + ((16 * r2) << sl);
        yc[dst] = make_float2(er[r2] * cw - ei[r2] * sw,
                              er[r2] * sw + ei[r2] * cw);
        float ncw = cw * u1r - sw * u1i;
        sw = cw * u1i + sw * u1r;
        cw = ncw;
    }
}

// ---------------------------------------------------------------------------
// FUSED final pass: radix-256 (s=2^16) + radix-2 (shfl) + real-FFT untangle.
// Block b: batch A = q in [16b, 16b+16), batch B = mirrored window 2^16 - q.
// Thread (f = i + 16p, k):
//   batch A: Z[jA], jA = qA + (k+16r2)*2^16 + p*2^24  (c = p slot)
//   batch B: Z[M-jA] via row (15-k) transpose read + c = 1-p radix-2 slot
// Untangle: E=(Zj+conj Zm)/2, O=-i(Zj-conj Zm)/2, X[j]=E+W_N^j O, X[j+M]=E-WO,
// X[M-j]=conj X[j+M], X[N-j]=conj X[j]. Anchors sweep q in [1,32768) exactly
// once; q=0 / q=2^15 self-mirror families skipped (rfft_cleanup handles them).
// W_N^j: sincos(j0<2^21 exact) * const W_N^{15*2^20} * (-i)^p, then 16-step
// conj-recurrence (step e^{+2pi i/64}).
// ---------------------------------------------------------------------------
__global__ __launch_bounds__(512) void fft256_last_fused(
    const float2* __restrict__ xc,   // pass-2 output, M = 2^25 complex
    float* __restrict__ xre,
    float* __restrict__ xim,
    int Nq,          // M/256 = 2^17
    float w_scale)   // -2*pi/N
{
    __shared__ float lds[32 * 257 + 4];

    const int tid = threadIdx.x;
    const int f   = tid & 31;
    const int k   = tid >> 5;
    const int i   = f & 15;
    const int p   = f >> 4;
    const int b   = blockIdx.x;
    const int M   = 1 << 25;

    const int qA = 16 * b + i;
    int qB = 65536 - 16 * b - i;
    if (qB == 65536) qB = 0;        // only b==0,i==0 (self-mirror, skipped)

    float zAr[16], zAi[16];

    // ================= batch A (q = qA): keep Z, c = p =================
    {
        const int t = qA + (p << 16);
        float ar[16], ai[16];
#pragma unroll
        for (int j2 = 0; j2 < 16; ++j2) {
            float2 v = xc[t + (k + 16 * j2) * Nq];
            ar[j2] = v.x; ai[j2] = v.y;
        }
        dft16(ar, ai);
        {   // W_512^{r1*(2k+p)}
            float ang = -PI2F * ((float)(2 * k + p) * (1.0f / 512.0f));
            float w1i, w1r; __sincosf(ang, &w1i, &w1r);
            float cw = w1r, sw = w1i;
#pragma unroll
            for (int r1 = 1; r1 < 16; ++r1) {
                float tr = ar[r1] * cw - ai[r1] * sw;
                ai[r1]   = ar[r1] * sw + ai[r1] * cw;
                ar[r1]   = tr;
                float ncw = cw * w1r - sw * w1i;
                sw = cw * w1i + sw * w1r; cw = ncw;
            }
        }
        const int wb = f * 257 + k * 16;
        const int rb = f * 257 + k;
        float er[16], ei[16];
#pragma unroll
        for (int r1 = 0; r1 < 16; ++r1) lds[wb + r1] = ar[r1];
        __syncthreads();
#pragma unroll
        for (int jj = 0; jj < 16; ++jj) er[jj] = lds[rb + jj * 16];
        __syncthreads();
#pragma unroll
        for (int r1 = 0; r1 < 16; ++r1) lds[wb + r1] = ai[r1];
        __syncthreads();
#pragma unroll
        for (int jj = 0; jj < 16; ++jj) ei[jj] = lds[rb + jj * 16];
        dft16(er, ei);
        {   // W_32^{p*r2}
            float ang2 = -PI2F * ((float)p * (1.0f / 32.0f));
            float u1i, u1r; __sincosf(ang2, &u1i, &u1r);
            float cw = u1r, sw = u1i;
#pragma unroll
            for (int r2 = 1; r2 < 16; ++r2) {
                float tr = er[r2] * cw - ei[r2] * sw;
                ei[r2]   = er[r2] * sw + ei[r2] * cw;
                er[r2]   = tr;
                float ncw = cw * u1r - sw * u1i;
                sw = cw * u1i + sw * u1r; cw = ncw;
            }
        }
        // radix-2 across p (lane^16); keep c = p slot
#pragma unroll
        for (int r2 = 0; r2 < 16; ++r2) {
            float orr = __shfl_xor(er[r2], 16);
            float oii = __shfl_xor(ei[r2], 16);
            zAr[r2] = p ? (orr - er[r2]) : (er[r2] + orr);
            zAi[r2] = p ? (oii - ei[r2]) : (ei[r2] + oii);
        }
    }
    __syncthreads();

    // ========= batch B (q = qB): rows 15-k, c = 1-p; untangle+write =========
    {
        const int t = qB + (p << 16);
        float ar[16], ai[16];
#pragma unroll
        for (int j2 = 0; j2 < 16; ++j2) {
            float2 v = xc[t + (k + 16 * j2) * Nq];
            ar[j2] = v.x; ai[j2] = v.y;
        }
        dft16(ar, ai);
        {
            float ang = -PI2F * ((float)(2 * k + p) * (1.0f / 512.0f));
            float w1i, w1r; __sincosf(ang, &w1i, &w1r);
            float cw = w1r, sw = w1i;
#pragma unroll
            for (int r1 = 1; r1 < 16; ++r1) {
                float tr = ar[r1] * cw - ai[r1] * sw;
                ai[r1]   = ar[r1] * sw + ai[r1] * cw;
                ar[r1]   = tr;
                float ncw = cw * w1r - sw * w1i;
                sw = cw * w1i + sw * w1r; cw = ncw;
            }
        }
        const int wb = f * 257 + k * 16;
        const int rb = f * 257 + (15 - k);     // mirrored r1 row
        float er[16], ei[16];
#pragma unroll
        for (int r1 = 0; r1 < 16; ++r1) lds[wb + r1] = ar[r1];
        __syncthreads();
#pragma unroll
        for (int jj = 0; jj < 16; ++jj) er[jj] = lds[rb + jj * 16];
        __syncthreads();
#pragma unroll
        for (int r1 = 0; r1 < 16; ++r1) lds[wb + r1] = ai[r1];
        __syncthreads();
#pragma unroll
        for (int jj = 0; jj < 16; ++jj) ei[jj] = lds[rb + jj * 16];
        dft16(er, ei);
        {
            float ang2 = -PI2F * ((float)p * (1.0f / 32.0f));
            float u1i, u1r; __sincosf(ang2, &u1i, &u1r);
            float cw = u1r, sw = u1i;
#pragma unroll
            for (int r2 = 1; r2 < 16; ++r2) {
                float tr = er[r2] * cw - ei[r2] * sw;
                ei[r2]   = er[r2] * sw + ei[r2] * cw;
                er[r2]   = tr;
                float ncw = cw * u1r - sw * u1i;
                sw = cw * u1i + sw * u1r; cw = ncw;
            }
        }

        // W = W_N^{j0 + 15*2^20} * (-i)^p ; j0 = qA + k*2^16 (exact in float)
        const float C15 = 0.0980171403295606f;   // cos(2*pi*15/64)
        const float S15 = 0.9951847266721969f;   // sin(2*pi*15/64)
        float ang0 = w_scale * (float)(qA + (k << 16));
        float s0, c0; __sincosf(ang0, &s0, &c0);
        float Wr = c0 * C15 + s0 * S15;
        float Wi = s0 * C15 - c0 * S15;
        if (p) { float tmp = Wr; Wr = Wi; Wi = -tmp; }   // * (-i)
        const bool doW = (qA != 0);

#pragma unroll
        for (int r2p = 0; r2p < 16; ++r2p) {
            float orr = __shfl_xor(er[r2p], 16);
            float oii = __shfl_xor(ei[r2p], 16);
            float Zmr = p ? (er[r2p] + orr) : (er[r2p] - orr);   // c = 1-p
            float Zmi = p ? (ei[r2p] + oii) : (ei[r2p] - oii);
            if (doW) {
                const int r2 = 15 - r2p;
                const int j  = qA + ((k + 16 * r2) << 16) + (p << 24);
                float Zjr = zAr[r2], Zji = zAi[r2];
                float Er = 0.5f * (Zjr + Zmr), Ei = 0.5f * (Zji - Zmi);
                float Or = 0.5f * (Zji + Zmi), Oi = 0.5f * (Zmr - Zjr);
                float WOr = Wr * Or - Wi * Oi, WOi = Wr * Oi + Wi * Or;
                float x1r = Er + WOr, x1i = Ei + WOi;   // X[j]
                float x2r = Er - WOr, x2i = Ei - WOi;   // X[j+M]
                xre[j]         = x1r;  xim[j]         = x1i;
                xre[j + M]     = x2r;  xim[j + M]     = x2i;
                xre[M - j]     = x2r;  xim[M - j]     = -x2i;
                xre[2 * M - j] = x1r;  xim[2 * M - j] = -x1i;
            }
            // W *= conj(W_N^{2^20}) = (cos(2pi/64), +sin(2pi/64))
            float nWr = Wr * S15 - Wi * C15;   // note cos(2pi/64)=S15, sin=C15
            Wi        = Wr * C15 + Wi * S15;
            Wr = nWr;
        }
    }
}

// ---------------------------------------------------------------------------
// Cleanup: the two self-mirror families (q-part 0 and 2^15) = 2048 outputs.
// One block: phase 1 computes the 4 special pass-3 sub-FFTs by direct DFT
// (t = 0, 2^16, 2^15, 2^15+2^16) into LDS; phase 2 replays the verified
// rfft_final algebra for k_old = r*2^16 (r<=128) and 2^15 + r*2^16 (r<128).
// ---------------------------------------------------------------------------
__global__ __launch_bounds__(512) void rfft_cleanup(const float2* __restrict__ xc,
                                                    float* __restrict__ xre,
                                                    float* __restrict__ xim,
                                                    int Nq, float w_scale)
{
    __shared__ float2 S[1024];   // [t_idx][r]: 0:q0p0 1:q0p1 2:q32768p0 3:q32768p1
    const int tid = threadIdx.x;

    for (int out = tid; out < 1024; out += 512) {
        const int ti = out >> 8, r = out & 255;
        const int t  = ((ti >> 1) << 15) + ((ti & 1) << 16);  // 0,65536,32768,98304
        float ang = -PI2F * ((float)r * (1.0f / 256.0f));
        float ws, wc; __sincosf(ang, &ws, &wc);
        float accr = 0.f, acci = 0.f, cr = 1.f, ci = 0.f;
        for (int j = 0; j < 256; ++j) {
            float2 v = xc[t + j * Nq];
            accr += v.x * cr - v.y * ci;
            acci += v.x * ci + v.y * cr;
            float nr = cr * wc - ci * ws;
            ci = cr * ws + ci * wc; cr = nr;
        }
        if (ti & 1) {   // * W_512^{p*r}
            float ang2 = -PI2F * ((float)r * (1.0f / 512.0f));
            float s2, c2; __sincosf(ang2, &s2, &c2);
            float nr = accr * c2 - acci * s2;
            acci = accr * s2 + acci * c2; accr = nr;
        }
        S[(ti << 8) + r] = make_float2(accr, acci);
    }
    __syncthreads();

    if (tid >= 257) return;
    const int K = 1 << 24, M = 1 << 25;

    if (tid == 0) {
        float2 A = S[0], B = S[256];
        float z0r = A.x + B.x, z0i = A.y + B.y;
        float zkr = A.x - B.x, zki = A.y - B.y;
        xre[0]     = z0r + z0i;  xim[0]     = 0.f;
        xre[M]     = z0r - z0i;  xim[M]     = 0.f;
        xre[K]     = zkr;        xim[K]     = -zki;
        xre[M + K] = zkr;        xim[M + K] = zki;
        return;
    }

    int kk; float2 A, B, C, D;
    if (tid <= 128) {
        const int r = tid;                      // q=0 family, r in [1,128]
        kk = r << 16;
        A = S[r];             B = S[256 + r];
        C = S[256 - r];       D = S[512 - r];
    } else {
        const int r = tid - 129;                // q=2^15 family, r in [0,127]
        kk = 32768 + (r << 16);
        A = S[512 + r];       B = S[768 + r];
        C = S[512 + 255 - r]; D = S[768 + 255 - r];
    }

    float Z1r = A.x + B.x, Z1i = A.y + B.y;
    float Zmr = C.x - D.x, Zmi = C.y - D.y;
    float Y1r = C.x + D.x, Y1i = C.y + D.y;
    float Ymr = A.x - B.x, Ymi = A.y - B.y;

    float ang = w_scale * (float)kk;
    float Wi_, Wr_;
    __sincosf(ang, &Wi_, &Wr_);

    {   // pair kappa = kk
        float Er = 0.5f * (Z1r + Zmr), Ei = 0.5f * (Z1i - Zmi);
        float Or = 0.5f * (Z1i + Zmi), Oi = 0.5f * (Zmr - Z1r);
        float WOr = Wr_ * Or - Wi_ * Oi, WOi = Wr_ * Oi + Wi_ * Or;
        float xr1 = Er + WOr, xi1 = Ei + WOi;
        float xr2 = Er - WOr, xi2 = Ei - WOi;
        xre[kk]         = xr1;  xim[kk]         = xi1;
        xre[kk + M]     = xr2;  xim[kk + M]     = xi2;
        xre[M - kk]     = xr2;  xim[M - kk]     = -xi2;
        xre[2 * M - kk] = xr1;  xim[2 * M - kk] = -xi1;
    }
    {   // pair kappa = K - kk, W' = -i*conj(W) = (-Wi_, -Wr_)
        float Wpr = -Wi_, Wpi = -Wr_;
        float Er = 0.5f * (Y1r + Ymr), Ei = 0.5f * (Y1i - Ymi);
        float Or = 0.5f * (Y1i + Ymi), Oi = 0.5f * (Ymr - Y1r);
        float WOr = Wpr * Or - Wpi * Oi, WOi = Wpr * Oi + Wpi * Or;
        float xr1 = Er + WOr, xi1 = Ei + WOi;
        float xr2 = Er - WOr, xi2 = Ei - WOi;
        xre[K - kk]         = xr1;  xim[K - kk]         = xi1;
        xre[K - kk + M]     = xr2;  xim[K - kk + M]     = xi2;
        xre[K + kk]         = xr2;  xim[K + kk]         = -xi2;
        xre[M + K + kk]     = xr1;  xim[M + K + kk]     = -xi1;
    }
}

// ---------------------------------------------------------------------------
// Fallback path kernels (non-2^26 sizes) — verified in earlier rounds.
// ---------------------------------------------------------------------------
__global__ __launch_bounds__(256) void fft4_first(const float* __restrict__ x,
                                                  float* __restrict__ yre,
                                                  float* __restrict__ yim,
                                                  int Nq, float n_inv)
{
    int p = blockIdx.x * 256 + threadIdx.x;
    if (p >= Nq) return;

    float a = x[p];
    float b = x[p + Nq];
    float c = x[p + 2 * Nq];
    float d = x[p + 3 * Nq];

    float apc = a + c, amc = a - c;
    float bpd = b + d, bmd = b - d;

    float ang = -PI2F * ((float)p * n_inv);
    float w1i, w1r;
    __sincosf(ang, &w1i, &w1r);
    float w2r = w1r * w1r - w1i * w1i, w2i = 2.f * w1r * w1i;
    float w3r = w2r * w1r - w2i * w1i, w3i = w2r * w1i + w2i * w1r;

    float t2 = apc - bpd;
    float4 r4, i4;
    r4.x = apc + bpd;                 i4.x = 0.f;
    r4.y = amc * w1r + bmd * w1i;     i4.y = amc * w1i - bmd * w1r;
    r4.z = t2 * w2r;                  i4.z = t2 * w2i;
    r4.w = amc * w3r - bmd * w3i;     i4.w = amc * w3i + bmd * w3r;

    *(float4*)(yre + 4 * p) = r4;
    *(float4*)(yim + 4 * p) = i4;
}

__global__ __launch_bounds__(256) void fft4_pass(const float* __restrict__ xre,
                                                 const float* __restrict__ xim,
                                                 float* __restrict__ yre,
                                                 float* __restrict__ yim,
                                                 int Nq, int sl, float n_inv)
{
    int t = blockIdx.x * 256 + threadIdx.x;
    if (t >= Nq) return;

    const int s = 1 << sl;
    const int q = t & (s - 1);
    const int p = t >> sl;

    float ar = xre[t],          ai = xim[t];
    float br = xre[t + Nq],     bi = xim[t + Nq];
    float cr = xre[t + 2 * Nq], ci = xim[t + 2 * Nq];
    float dr = xre[t + 3 * Nq], di = xim[t + 3 * Nq];

    float apcr = ar + cr, apci = ai + ci;
    float amcr = ar - cr, amci = ai - ci;
    float bpdr = br + dr, bpdi = bi + di;
    float bmdr = br - dr, bmdi = bi - di;

    float ang = -PI2F * ((float)p * n_inv);
    float w1i, w1r;
    __sincosf(ang, &w1i, &w1r);
    float w2r = w1r * w1r - w1i * w1i, w2i = 2.f * w1r * w1i;
    float w3r = w2r * w1r - w2i * w1i, w3i = w2r * w1i + w2i * w1r;

    const int dst = q + (p << (sl + 2));

    yre[dst] = apcr + bpdr;
    yim[dst] = apci + bpdi;

    float t1r = amcr + bmdi, t1i = amci - bmdr;
    yre[dst + s] = t1r * w1r - t1i * w1i;
    yim[dst + s] = t1r * w1i + t1i * w1r;

    float t2r = apcr - bpdr, t2i = apci - bpdi;
    yre[dst + 2 * s] = t2r * w2r - t2i * w2i;
    yim[dst + 2 * s] = t2r * w2i + t2i * w2r;

    float t3r = amcr - bmdi, t3i = amci + bmdr;
    yre[dst + 3 * s] = t3r * w3r - t3i * w3i;
    yim[dst + 3 * s] = t3r * w3i + t3i * w3r;
}

__global__ __launch_bounds__(256) void bitrev_load(const float* __restrict__ x,
                                                   float* __restrict__ re,
                                                   float* __restrict__ im,
                                                   int N, int logN)
{
    int i = blockIdx.x * 256 + threadIdx.x;
    if (i >= N) return;
    unsigned r = __brev((unsigned)i) >> (32 - logN);
    re[i] = x[r];
    im[i] = 0.f;
}

__global__ __launch_bounds__(256) void r2_stage(float* __restrict__ re,
                                                float* __restrict__ im,
                                                int Nh, int sl, float m_inv)
{
    int t = blockIdx.x * 256 + threadIdx.x;
    if (t >= Nh) return;
    const int half = 1 << sl;
    const int j = t & (half - 1);
    const int pos = ((t >> sl) << (sl + 1)) + j;

    float ang = -PI2F * ((float)j * m_inv);
    float wi, wr;
    __sincosf(ang, &wi, &wr);

    float ur = re[pos],         ui = im[pos];
    float vr0 = re[pos + half], vi0 = im[pos + half];
    float vr = vr0 * wr - vi0 * wi;
    float vi = vr0 * wi + vi0 * wr;

    re[pos] = ur + vr;         im[pos] = ui + vi;
    re[pos + half] = ur - vr;  im[pos + half] = ui - vi;
}

// ---------------------------------------------------------------------------

extern "C" void kernel_launch(void* const* d_in, const int* in_sizes, int n_in,
                              void* d_out, int out_size, void* d_ws, size_t ws_size,
                              hipStream_t stream)
{
    const float* x = (const float*)d_in[0];
    const int N = in_sizes[0];
    int logN = 0;
    while ((1 << logN) < N) ++logN;

    float* outre = (float*)d_out;
    float* outim = outre + N;

    if (logN == 26 && ws_size >= (size_t)(N / 2) * sizeof(float2)) {
        // Real-input FFT, M = N/2 = 2^25 complex points (float2 view of x).
        // Schedule: radix-256 (s=1) -> radix-256 (s=256) -> FUSED
        // {radix-256 (s=2^16) + radix-2 + untangle} + tiny cleanup.
        // Buffers: din -> d_out(scratch) -> ws -> d_out(final X). The fused
        // pass reads only ws, so X writes into d_out cannot race its reads.
        const int M  = N >> 1;           // 2^25
        const int Nq = M >> 8;           // 2^17
        const float fM = (float)M;
        const float wsc = -PI2F / (float)N;

        const float2* zc = (const float2*)x;
        float2* wc = (float2*)d_ws;
        float2* oc = (float2*)d_out;     // scratch region (overwritten later)

        // pass 1: s = 1   (din -> d_out scratch)
        hipLaunchKernelGGL(fft256_first, dim3(M >> 12), dim3(256), 0, stream,
                           zc, oc, Nq, 1.0f / fM, 16.0f / fM);
        // pass 2: s = 256 (d_out scratch -> ws)
        hipLaunchKernelGGL(fft256_mid, dim3(M >> 13), dim3(512), 0, stream,
                           oc, wc, Nq, 8, 256.0f / fM, 4096.0f / fM);
        // pass 3 fused: (ws -> d_out split re/im), generic mirror pairs
        hipLaunchKernelGGL(fft256_last_fused, dim3(M >> 14), dim3(512), 0,
                           stream, wc, outre, outim, Nq, wsc);
        // cleanup: q=0 and q=2^15 self-mirror families (ws -> d_out)
        hipLaunchKernelGGL(rfft_cleanup, dim3(1), dim3(512), 0, stream,
                           wc, outre, outim, Nq, wsc);
    } else if (((logN & 1) == 0) &&
               ws_size >= (size_t)2 * (size_t)N * sizeof(float)) {
        // Generic radix-4 Stockham (verified path).
        float* wre = (float*)d_ws;
        float* wim = wre + N;
        const int Nq = N >> 2;
        const int nb = (Nq + 255) / 256;
        hipLaunchKernelGGL(fft4_first, dim3(nb), dim3(256), 0, stream,
                           x, outre, outim, Nq, 1.0f / (float)N);
        float* sre = outre; float* sim = outim;
        float* dre = wre;   float* dim_ = wim;
        const int npass = logN >> 1;
        for (int i = 2; i <= npass; ++i) {
            const int sl = 2 * (i - 1);
            const float n_inv = 1.0f / (float)(N >> sl);
            hipLaunchKernelGGL(fft4_pass, dim3(nb), dim3(256), 0, stream,
                               sre, sim, dre, dim_, Nq, sl, n_inv);
            float* tt;
            tt = sre; sre = dre; dre = tt;
            tt = sim; sim = dim_; dim_ = tt;
        }
    } else {
        const int nbN = (N + 255) / 256;
        hipLaunchKernelGGL(bitrev_load, dim3(nbN), dim3(256), 0, stream,
                           x, outre, outim, N, logN);
        const int Nh = N >> 1;
        const int nbh = (Nh + 255) / 256;
        for (int s = 0; s < logN; ++s) {
            const float m_inv = 1.0f / (float)(2 << s);
            hipLaunchKernelGGL(r2_stage, dim3(nbh), dim3(256), 0, stream,
                               outre, outim, Nh, s, m_inv);
        }
    }
}

// Round 11
// 490.694 us; speedup vs baseline: 1.6417x; 1.6417x over previous
//
#include <hip/hip_runtime.h>

#define PI2F 6.283185307179586476f

// ---------------------------------------------------------------------------
// Non-temporal (cache-bypass) access helpers. All four hot kernels stream
// 512MB+ with zero reuse -- bypassing L2 avoids write-allocate thrash.
// float2 via native ext_vector (HIP float2 is a struct; builtin needs vector).
// ---------------------------------------------------------------------------
typedef float nvf2 __attribute__((ext_vector_type(2)));

__device__ __forceinline__ float2 ntload2(const float2* p) {
    nvf2 v = __builtin_nontemporal_load((const nvf2*)p);
    return make_float2(v.x, v.y);
}
__device__ __forceinline__ void ntstore2(float2* p, float2 q) {
    nvf2 v; v.x = q.x; v.y = q.y;
    __builtin_nontemporal_store(v, (nvf2*)p);
}
__device__ __forceinline__ void ntstoref(float* p, float v) {
    __builtin_nontemporal_store(v, p);
}

// ---------------------------------------------------------------------------
// 16-point DFT, natural order in/out, fully unrolled (two radix-4 layers).
// X[r] = sum_j a[j] W_16^{jr}.
// ---------------------------------------------------------------------------
__device__ __forceinline__ void dft16(float* xr, float* xi)
{
    const float W16R[16] = {1.f, 1.f, 1.f, 1.f,
                            1.f, 0.92387953251f, 0.70710678119f, 0.38268343236f,
                            1.f, 0.70710678119f, 0.f, -0.70710678119f,
                            1.f, 0.38268343236f, -0.70710678119f, -0.92387953251f};
    const float W16I[16] = {0.f, 0.f, 0.f, 0.f,
                            0.f, -0.38268343236f, -0.70710678119f, -0.92387953251f,
                            0.f, -0.70710678119f, -1.f, -0.70710678119f,
                            0.f, -0.92387953251f, -0.70710678119f, 0.38268343236f};

    float br[16], bi[16];
#pragma unroll
    for (int jl = 0; jl < 4; ++jl) {
        float a0r = xr[jl],      a0i = xi[jl];
        float a1r = xr[jl + 4],  a1i = xi[jl + 4];
        float a2r = xr[jl + 8],  a2i = xi[jl + 8];
        float a3r = xr[jl + 12], a3i = xi[jl + 12];
        float s02r = a0r + a2r, s02i = a0i + a2i;
        float d02r = a0r - a2r, d02i = a0i - a2i;
        float s13r = a1r + a3r, s13i = a1i + a3i;
        float d13r = a1r - a3r, d13i = a1i - a3i;
        br[jl + 0]  = s02r + s13r;  bi[jl + 0]  = s02i + s13i;
        br[jl + 4]  = d02r + d13i;  bi[jl + 4]  = d02i - d13r;
        br[jl + 8]  = s02r - s13r;  bi[jl + 8]  = s02i - s13i;
        br[jl + 12] = d02r - d13i;  bi[jl + 12] = d02i + d13r;
    }
#pragma unroll
    for (int pos = 0; pos < 16; ++pos) {
        float wr = W16R[pos], wi = W16I[pos];
        float tr = br[pos] * wr - bi[pos] * wi;
        bi[pos]  = br[pos] * wi + bi[pos] * wr;
        br[pos]  = tr;
    }
#pragma unroll
    for (int rl = 0; rl < 4; ++rl) {
        float a0r = br[4 * rl + 0], a0i = bi[4 * rl + 0];
        float a1r = br[4 * rl + 1], a1i = bi[4 * rl + 1];
        float a2r = br[4 * rl + 2], a2i = bi[4 * rl + 2];
        float a3r = br[4 * rl + 3], a3i = bi[4 * rl + 3];
        float s02r = a0r + a2r, s02i = a0i + a2i;
        float d02r = a0r - a2r, d02i = a0i - a2i;
        float s13r = a1r + a3r, s13i = a1i + a3i;
        float d13r = a1r - a3r, d13i = a1i - a3i;
        xr[rl + 0]  = s02r + s13r;  xi[rl + 0]  = s02i + s13i;
        xr[rl + 4]  = d02r + d13i;  xi[rl + 4]  = d02i - d13r;
        xr[rl + 8]  = s02r - s13r;  xi[rl + 8]  = s02i - s13i;
        xr[rl + 12] = d02r - d13i;  xi[rl + 12] = d02i + d13r;
    }
}

// ---------------------------------------------------------------------------
// Pass 1 (s = 1): radix-256 Stockham with LDS-staged contiguous stores (r8).
// ---------------------------------------------------------------------------
__global__ __launch_bounds__(256) void fft256_first(const float2* __restrict__ xc,
                                                    float2* __restrict__ yc,
                                                    int Nq,         // M/256
                                                    float m_inv,    // 1/M
                                                    float m16_inv)  // 16/M
{
    __shared__ __align__(16) float lds[16 * 260 + 4];

    const int tid = threadIdx.x;
    const int f   = tid & 15;
    const int k   = tid >> 4;
    const int t   = blockIdx.x * 16 + f;

    float ar[16], ai[16];
#pragma unroll
    for (int j2 = 0; j2 < 16; ++j2) {
        float2 v = ntload2(&xc[t + (k + 16 * j2) * Nq]);
        ar[j2] = v.x;
        ai[j2] = v.y;
    }

    dft16(ar, ai);

    {
        const float mf = (float)(k * Nq + t);
        float ang = -PI2F * (mf * m_inv);
        float w1i, w1r;
        __sincosf(ang, &w1i, &w1r);
        float cw = w1r, sw = w1i;
#pragma unroll
        for (int r1 = 1; r1 < 16; ++r1) {
            float tr = ar[r1] * cw - ai[r1] * sw;
            ai[r1]   = ar[r1] * sw + ai[r1] * cw;
            ar[r1]   = tr;
            float ncw = cw * w1r - sw * w1i;
            sw = cw * w1i + sw * w1r;
            cw = ncw;
        }
    }

    const int wbase = f * 260 + k * 16;
    const int rbase = f * 260 + k;

    float er[16], ei[16];

#pragma unroll
    for (int v = 0; v < 4; ++v)
        *(float4*)&lds[wbase + 4 * v] =
            make_float4(ar[4 * v], ar[4 * v + 1], ar[4 * v + 2], ar[4 * v + 3]);
    __syncthreads();
#pragma unroll
    for (int jj = 0; jj < 16; ++jj)
        er[jj] = lds[rbase + jj * 16];
    __syncthreads();

#pragma unroll
    for (int v = 0; v < 4; ++v)
        *(float4*)&lds[wbase + 4 * v] =
            make_float4(ai[4 * v], ai[4 * v + 1], ai[4 * v + 2], ai[4 * v + 3]);
    __syncthreads();
#pragma unroll
    for (int jj = 0; jj < 16; ++jj)
        ei[jj] = lds[rbase + jj * 16];

    dft16(er, ei);

    {
        float ang2 = -PI2F * ((float)t * m16_inv);
        float u1i, u1r;
        __sincosf(ang2, &u1i, &u1r);
        float cw = u1r, sw = u1i;
#pragma unroll
        for (int r2 = 1; r2 < 16; ++r2) {
            float tr = er[r2] * cw - ei[r2] * sw;
            ei[r2]   = er[r2] * sw + ei[r2] * cw;
            er[r2]   = tr;
            float ncw = cw * u1r - sw * u1i;
            sw = cw * u1i + sw * u1r;
            cw = ncw;
        }
    }

    float2* img = (float2*)lds;
    __syncthreads();
#pragma unroll
    for (int b = 0; b < 2; ++b) {
        if ((f >> 3) == b) {
            const int fr = f & 7;
#pragma unroll
            for (int r2 = 0; r2 < 16; ++r2)
                img[fr * 258 + k + 16 * r2] = make_float2(er[r2], ei[r2]);
        }
        __syncthreads();
        const int base = (blockIdx.x * 16 + 8 * b) * 256;
#pragma unroll
        for (int i = 0; i < 8; ++i)
            ntstore2(&yc[base + i * 256 + tid], img[i * 258 + tid]);
        if (b == 0) __syncthreads();
    }
}

// ---------------------------------------------------------------------------
// Middle passes (s = 256, 65536): radix-256 Stockham, 512 threads =
// 32 f (consecutive t) x 16 k (r9). 2 x 256B segments per wave-instruction
// on loads and stores. LDS stride-257 rows -> 2 lanes/bank (free).
// Plain launch_bounds (r5 spill lesson).
// ---------------------------------------------------------------------------
__global__ __launch_bounds__(512) void fft256_mid(const float2* __restrict__ xc,
                                                  float2* __restrict__ yc,
                                                  int Nq,        // M/256
                                                  int sl,        // log2(s)
                                                  float n_inv,   // 1/n
                                                  float n16_inv) // 16/n
{
    __shared__ float lds[32 * 257 + 4];

    const int tid = threadIdx.x;
    const int f   = tid & 31;
    const int k   = tid >> 5;
    const int t   = blockIdx.x * 32 + f;
    const int s   = 1 << sl;
    const int q   = t & (s - 1);
    const int p   = t >> sl;

    float ar[16], ai[16];
#pragma unroll
    for (int j2 = 0; j2 < 16; ++j2) {
        float2 v = ntload2(&xc[t + (k + 16 * j2) * Nq]);
        ar[j2] = v.x;
        ai[j2] = v.y;
    }

    dft16(ar, ai);

    {
        const int   m  = k * (Nq >> sl) + p;
        float ang = -PI2F * ((float)m * n_inv);
        float w1i, w1r;
        __sincosf(ang, &w1i, &w1r);
        float cw = w1r, sw = w1i;
#pragma unroll
        for (int r1 = 1; r1 < 16; ++r1) {
            float tr = ar[r1] * cw - ai[r1] * sw;
            ai[r1]   = ar[r1] * sw + ai[r1] * cw;
            ar[r1]   = tr;
            float ncw = cw * w1r - sw * w1i;
            sw = cw * w1i + sw * w1r;
            cw = ncw;
        }
    }

    const int wbase = f * 257 + k * 16;
    const int rbase = f * 257 + k;

    float er[16], ei[16];

#pragma unroll
    for (int r1 = 0; r1 < 16; ++r1)
        lds[wbase + r1] = ar[r1];
    __syncthreads();
#pragma unroll
    for (int jj = 0; jj < 16; ++jj)
        er[jj] = lds[rbase + jj * 16];
    __syncthreads();

#pragma unroll
    for (int r1 = 0; r1 < 16; ++r1)
        lds[wbase + r1] = ai[r1];
    __syncthreads();
#pragma unroll
    for (int jj = 0; jj < 16; ++jj)
        ei[jj] = lds[rbase + jj * 16];

    dft16(er, ei);

    const int dstbase = q + ((256 * p + k) << sl);
    float ang2 = -PI2F * ((float)p * n16_inv);
    float u1i, u1r;
    __sincosf(ang2, &u1i, &u1r);

    ntstore2(&yc[dstbase], make_float2(er[0], ei[0]));
    float cw = u1r, sw = u1i;
#pragma unroll
    for (int r2 = 1; r2 < 16; ++r2) {
        int dst = dstbase + ((16 * r2) << sl);
        ntstore2(&yc[dst], make_float2(er[r2] * cw - ei[r2] * sw,
                                       er[r2] * sw + ei[r2] * cw));
        float ncw = cw * u1r - sw * u1i;
        sw = cw * u1i + sw * u1r;
        cw = ncw;
    }
}

// ---------------------------------------------------------------------------
// Final pass of the real-input FFT: fused (last radix-2 Stockham stage) +
// (real-FFT untangle), Zp (M=2^25 complex, pre-radix-2) -> X (N=2^26, split).
// Verified r7. Writes are 1KB-contiguous runs across lanes (5.9 TB/s).
// ---------------------------------------------------------------------------
__global__ __launch_bounds__(256) void rfft_final(const float2* __restrict__ Zp,
                                                  float* __restrict__ xre,
                                                  float* __restrict__ xim,
                                                  int K,          // M/2 = N/4
                                                  float w_scale)  // -2*pi/N
{
    const int k = blockIdx.x * 256 + threadIdx.x;
    const int half = K >> 1;
    if (k > half) return;
    const int M = K << 1;

    if (k == 0) {
        float2 A = Zp[0], B = Zp[K];
        float z0r = A.x + B.x, z0i = A.y + B.y;   // Z[0]
        float zkr = A.x - B.x, zki = A.y - B.y;   // Z[K]
        xre[0]     = z0r + z0i;  xim[0]     = 0.f;          // X[0]
        xre[M]     = z0r - z0i;  xim[M]     = 0.f;          // X[M] (Nyquist)
        xre[K]     = zkr;        xim[K]     = -zki;         // X[K]   = conj Z[K]
        xre[M + K] = zkr;        xim[M + K] = zki;          // X[M+K] = Z[K]
        return;
    }

    float2 A = ntload2(&Zp[k]);
    float2 B = ntload2(&Zp[k + K]);
    float2 C = ntload2(&Zp[K - k]);
    float2 D = ntload2(&Zp[M - k]);

    float Z1r = A.x + B.x, Z1i = A.y + B.y;   // Z[k]
    float Zmr = C.x - D.x, Zmi = C.y - D.y;   // Z[M-k]
    float Y1r = C.x + D.x, Y1i = C.y + D.y;   // Z[K-k]
    float Ymr = A.x - B.x, Ymi = A.y - B.y;   // Z[K+k]

    float ang = w_scale * (float)k;           // -2*pi*k/N
    float Wi, Wr;
    __sincosf(ang, &Wi, &Wr);

    // pair kappa = k
    {
        float Er = 0.5f * (Z1r + Zmr), Ei = 0.5f * (Z1i - Zmi);
        float Or = 0.5f * (Z1i + Zmi), Oi = 0.5f * (Zmr - Z1r);
        float WOr = Wr * Or - Wi * Oi, WOi = Wr * Oi + Wi * Or;
        float xr1 = Er + WOr, xi1 = Ei + WOi;   // X[k]
        float xr2 = Er - WOr, xi2 = Ei - WOi;   // X[k+M]
        ntstoref(&xre[k],         xr1);  ntstoref(&xim[k],         xi1);
        ntstoref(&xre[k + M],     xr2);  ntstoref(&xim[k + M],     xi2);
        ntstoref(&xre[M - k],     xr2);  ntstoref(&xim[M - k],     -xi2);
        ntstoref(&xre[2 * M - k], xr1);  ntstoref(&xim[2 * M - k], -xi1);
    }
    // pair kappa = K - k,  W' = -i * conj(W) = (-Wi, -Wr)
    {
        float Wpr = -Wi, Wpi = -Wr;
        float Er = 0.5f * (Y1r + Ymr), Ei = 0.5f * (Y1i - Ymi);
        float Or = 0.5f * (Y1i + Ymi), Oi = 0.5f * (Ymr - Y1r);
        float WOr = Wpr * Or - Wpi * Oi, WOi = Wpr * Oi + Wpi * Or;
        float xr1 = Er + WOr, xi1 = Ei + WOi;   // X[K-k]
        float xr2 = Er - WOr, xi2 = Ei - WOi;   // X[K-k+M]
        ntstoref(&xre[K - k],     xr1);  ntstoref(&xim[K - k],     xi1);
        ntstoref(&xre[K - k + M], xr2);  ntstoref(&xim[K - k + M], xi2);
        ntstoref(&xre[K + k],     xr2);  ntstoref(&xim[K + k],     -xi2);
        ntstoref(&xre[M + K + k], xr1);  ntstoref(&xim[M + K + k], -xi1);
    }
}

// ---------------------------------------------------------------------------
// Fallback path kernels (non-2^26 sizes) — verified in earlier rounds.
// ---------------------------------------------------------------------------
__global__ __launch_bounds__(256) void fft4_first(const float* __restrict__ x,
                                                  float* __restrict__ yre,
                                                  float* __restrict__ yim,
                                                  int Nq, float n_inv)
{
    int p = blockIdx.x * 256 + threadIdx.x;
    if (p >= Nq) return;

    float a = x[p];
    float b = x[p + Nq];
    float c = x[p + 2 * Nq];
    float d = x[p + 3 * Nq];

    float apc = a + c, amc = a - c;
    float bpd = b + d, bmd = b - d;

    float ang = -PI2F * ((float)p * n_inv);
    float w1i, w1r;
    __sincosf(ang, &w1i, &w1r);
    float w2r = w1r * w1r - w1i * w1i, w2i = 2.f * w1r * w1i;
    float w3r = w2r * w1r - w2i * w1i, w3i = w2r * w1i + w2i * w1r;

    float t2 = apc - bpd;
    float4 r4, i4;
    r4.x = apc + bpd;                 i4.x = 0.f;
    r4.y = amc * w1r + bmd * w1i;     i4.y = amc * w1i - bmd * w1r;
    r4.z = t2 * w2r;                  i4.z = t2 * w2i;
    r4.w = amc * w3r - bmd * w3i;     i4.w = amc * w3i + bmd * w3r;

    *(float4*)(yre + 4 * p) = r4;
    *(float4*)(yim + 4 * p) = i4;
}

__global__ __launch_bounds__(256) void fft4_pass(const float* __restrict__ xre,
                                                 const float* __restrict__ xim,
                                                 float* __restrict__ yre,
                                                 float* __restrict__ yim,
                                                 int Nq, int sl, float n_inv)
{
    int t = blockIdx.x * 256 + threadIdx.x;
    if (t >= Nq) return;

    const int s = 1 << sl;
    const int q = t & (s - 1);
    const int p = t >> sl;

    float ar = xre[t],          ai = xim[t];
    float br = xre[t + Nq],     bi = xim[t + Nq];
    float cr = xre[t + 2 * Nq], ci = xim[t + 2 * Nq];
    float dr = xre[t + 3 * Nq], di = xim[t + 3 * Nq];

    float apcr = ar + cr, apci = ai + ci;
    float amcr = ar - cr, amci = ai - ci;
    float bpdr = br + dr, bpdi = bi + di;
    float bmdr = br - dr, bmdi = bi - di;

    float ang = -PI2F * ((float)p * n_inv);
    float w1i, w1r;
    __sincosf(ang, &w1i, &w1r);
    float w2r = w1r * w1r - w1i * w1i, w2i = 2.f * w1r * w1i;
    float w3r = w2r * w1r - w2i * w1i, w3i = w2r * w1i + w2i * w1r;

    const int dst = q + (p << (sl + 2));

    yre[dst] = apcr + bpdr;
    yim[dst] = apci + bpdi;

    float t1r = amcr + bmdi, t1i = amci - bmdr;
    yre[dst + s] = t1r * w1r - t1i * w1i;
    yim[dst + s] = t1r * w1i + t1i * w1r;

    float t2r = apcr - bpdr, t2i = apci - bpdi;
    yre[dst + 2 * s] = t2r * w2r - t2i * w2i;
    yim[dst + 2 * s] = t2r * w2i + t2i * w2r;

    float t3r = amcr - bmdi, t3i = amci + bmdr;
    yre[dst + 3 * s] = t3r * w3r - t3i * w3i;
    yim[dst + 3 * s] = t3r * w3i + t3i * w3r;
}

__global__ __launch_bounds__(256) void bitrev_load(const float* __restrict__ x,
                                                   float* __restrict__ re,
                                                   float* __restrict__ im,
                                                   int N, int logN)
{
    int i = blockIdx.x * 256 + threadIdx.x;
    if (i >= N) return;
    unsigned r = __brev((unsigned)i) >> (32 - logN);
    re[i] = x[r];
    im[i] = 0.f;
}

__global__ __launch_bounds__(256) void r2_stage(float* __restrict__ re,
                                                float* __restrict__ im,
                                                int Nh, int sl, float m_inv)
{
    int t = blockIdx.x * 256 + threadIdx.x;
    if (t >= Nh) return;
    const int half = 1 << sl;
    const int j = t & (half - 1);
    const int pos = ((t >> sl) << (sl + 1)) + j;

    float ang = -PI2F * ((float)j * m_inv);
    float wi, wr;
    __sincosf(ang, &wi, &wr);

    float ur = re[pos],         ui = im[pos];
    float vr0 = re[pos + half], vi0 = im[pos + half];
    float vr = vr0 * wr - vi0 * wi;
    float vi = vr0 * wi + vi0 * wr;

    re[pos] = ur + vr;         im[pos] = ui + vi;
    re[pos + half] = ur - vr;  im[pos + half] = ui - vi;
}

// ---------------------------------------------------------------------------

extern "C" void kernel_launch(void* const* d_in, const int* in_sizes, int n_in,
                              void* d_out, int out_size, void* d_ws, size_t ws_size,
                              hipStream_t stream)
{
    const float* x = (const float*)d_in[0];
    const int N = in_sizes[0];
    int logN = 0;
    while ((1 << logN) < N) ++logN;

    float* outre = (float*)d_out;
    float* outim = outre + N;

    if (logN == 26 && ws_size >= (size_t)(N / 2) * sizeof(float2)) {
        // Real-input FFT: z = float2 view of x (M = N/2 complex points).
        // M = 2^25: three radix-256 Stockham passes (s=1,256,65536) + fused
        // (radix-2 + untangle) final pass. (r9 structure — r10's mirror-fused
        // tail regressed: 64B-scatter X writes + 1.25x write amplification.)
        // Buffers: din -> ws -> dout_lo(scratch) -> ws -> dout(split re/im).
        const int M  = N >> 1;           // 2^25
        const int K  = M >> 1;           // 2^24
        const int Nq = M >> 8;           // 2^17
        const float fM = (float)M;

        const float2* zc = (const float2*)x;
        float2* wc = (float2*)d_ws;
        float2* oc = (float2*)d_out;     // lower 256MB of d_out as scratch

        // pass 1: s = 1      (din -> ws), 256-thr staged-store variant
        hipLaunchKernelGGL(fft256_first, dim3(M >> 12), dim3(256), 0, stream,
                           zc, wc, Nq, 1.0f / fM, 16.0f / fM);
        // pass 2: s = 256    (ws -> dout scratch), 512-thr wide-tile variant
        hipLaunchKernelGGL(fft256_mid, dim3(M >> 13), dim3(512), 0, stream,
                           wc, oc, Nq, 8, 256.0f / fM, 4096.0f / fM);
        // pass 3: s = 65536  (dout scratch -> ws)
        hipLaunchKernelGGL(fft256_mid, dim3(M >> 13), dim3(512), 0, stream,
                           oc, wc, Nq, 16, 65536.0f / fM, 1048576.0f / fM);
        // final: fused radix-2 + untangle (ws -> dout split re/im; writes all)
        const int nthreads = (K >> 1) + 1;
        hipLaunchKernelGGL(rfft_final, dim3((nthreads + 255) / 256), dim3(256),
                           0, stream,
                           wc, outre, outim, K, -PI2F / (float)N);
    } else if (((logN & 1) == 0) &&
               ws_size >= (size_t)2 * (size_t)N * sizeof(float)) {
        // Generic radix-4 Stockham (verified path).
        float* wre = (float*)d_ws;
        float* wim = wre + N;
        const int Nq = N >> 2;
        const int nb = (Nq + 255) / 256;
        hipLaunchKernelGGL(fft4_first, dim3(nb), dim3(256), 0, stream,
                           x, outre, outim, Nq, 1.0f / (float)N);
        float* sre = outre; float* sim = outim;
        float* dre = wre;   float* dim_ = wim;
        const int npass = logN >> 1;
        for (int i = 2; i <= npass; ++i) {
            const int sl = 2 * (i - 1);
            const float n_inv = 1.0f / (float)(N >> sl);
            hipLaunchKernelGGL(fft4_pass, dim3(nb), dim3(256), 0, stream,
                               sre, sim, dre, dim_, Nq, sl, n_inv);
            float* tt;
            tt = sre; sre = dre; dre = tt;
            tt = sim; sim = dim_; dim_ = tt;
        }
    } else {
        const int nbN = (N + 255) / 256;
        hipLaunchKernelGGL(bitrev_load, dim3(nbN), dim3(256), 0, stream,
                           x, outre, outim, N, logN);
        const int Nh = N >> 1;
        const int nbh = (Nh + 255) / 256;
        for (int s = 0; s < logN; ++s) {
            const float m_inv = 1.0f / (float)(2 << s);
            hipLaunchKernelGGL(r2_stage, dim3(nbh), dim3(256), 0, stream,
                               outre, outim, Nh, s, m_inv);
        }
    }
}